// Round 7
// baseline (419.935 us; speedup 1.0000x reference)
//
#include <hip/hip_runtime.h>

#define NN    50000
#define DD    128
#define RR    3
#define EE    800000
#define OUTD  64
#define BKT   128                 // nodes per bucket (dst and src binning)
#define NBK   391                 // ceil(NN/BKT)
#define CAP   2560                // per-bucket edge capacity, 4B dst-entries
#define CAPB  2560                // per-bucket edge capacity, 2B src-entries
#define CHUNK 8192                // edges per bin block (98 same-address reserve atomics/counter)
#define NCH   98                  // ceil(EE/CHUNK)
#define NPB   3125                // NN/16 pull blocks per relation
#define SETUPB 6250               // NN*DD/4/256 setup blocks
#define ALPHA_ 0.5f
#define SLOPE_ 0.01f
#define BETA1_ 0.6931471805599453f   // log(2)
#define BETA2_ 0.4054651081081644f   // log(1.5)

typedef __attribute__((ext_vector_type(8))) short short8;   // 8 bf16 = 4 VGPRs
typedef __attribute__((ext_vector_type(4))) float f32x4;
typedef __attribute__((ext_vector_type(4))) unsigned int u32x4;

__device__ __forceinline__ unsigned short f2b(float f) {   // fp32 -> bf16 RNE
    unsigned int u = __builtin_bit_cast(unsigned int, f);
    u += 0x7FFFu + ((u >> 16) & 1u);
    return (unsigned short)(u >> 16);
}
__device__ __forceinline__ unsigned int pack2(float lo, float hi) {
    return (unsigned int)f2b(lo) | ((unsigned int)f2b(hi) << 16);
}
__device__ __forceinline__ float blo(unsigned int w) { return __builtin_bit_cast(float, w << 16); }
__device__ __forceinline__ float bhi(unsigned int w) { return __builtin_bit_cast(float, w & 0xFFFF0000u); }

// ---------------- binning: phase-split LDS bucket-sort (A: by dst>>7, B: by src>>7) ----------------
__global__ __launch_bounds__(256) void bin_kernel(
    const int* __restrict__ src, const int* __restrict__ dst,
    int* __restrict__ bcnt_d, int* __restrict__ bcnt_s,
    int* __restrict__ pairs_d, unsigned short* __restrict__ pairs_s)
{
    __shared__ int hist[NBK];
    __shared__ int lbase[NBK];
    __shared__ int gdelta[NBK];
    __shared__ int lcur[NBK];
    __shared__ unsigned int staging[CHUNK];
    unsigned short* staging16 = (unsigned short*)staging;
    const int tid = threadIdx.x;
    const int blk = blockIdx.x;
    const int phase = (blk >= RR * NCH);
    const int rb = phase ? blk - RR * NCH : blk;
    const int r = rb / NCH;
    const int chunk = rb % NCH;
    const int e0 = chunk * CHUNK;
    const int n = min(CHUNK, EE - e0);
    const int* sp = src + (size_t)r * EE + e0;
    const int* dp = dst + (size_t)r * EE + e0;
    const int* kp = phase ? sp : dp;         // key stream for this phase

    for (int i = tid; i < NBK; i += 256) hist[i] = 0;
    __syncthreads();
    for (int i = tid; i < n; i += 256)
        atomicAdd(&hist[kp[i] >> 7], 1);
    __syncthreads();
    if (tid < 64) {
        int carry = 0;
        for (int c0 = 0; c0 < NBK; c0 += 64) {
            const int idx = c0 + tid;
            const int v = (idx < NBK) ? hist[idx] : 0;
            int incl = v;
            #pragma unroll
            for (int d = 1; d < 64; d <<= 1) {
                const int t = __shfl_up(incl, d, 64);
                if (tid >= d) incl += t;
            }
            if (idx < NBK) lbase[idx] = carry + incl - v;
            carry += __shfl(incl, 63, 64);
        }
    }
    __syncthreads();
    if (!phase) {
        for (int b = tid; b < NBK; b += 256) {
            lcur[b] = lbase[b];
            const int h = hist[b];
            if (h > 0) {
                const int gstart = (r * NBK + b) * CAP + atomicAdd(&bcnt_d[r * NBK + b], h);
                gdelta[b] = gstart - lbase[b];
            }
        }
        __syncthreads();
        for (int i = tid; i < n; i += 256) {
            const int d = dp[i];
            const int b = d >> 7;
            const int pos = atomicAdd(&lcur[b], 1);
            staging[pos] = (unsigned int)sp[i] | ((unsigned int)(d & 127) << 16)
                         | ((unsigned int)b << 23);
        }
        __syncthreads();
        for (int j = tid; j < n; j += 256) {
            const unsigned int v = staging[j];
            const int b = v >> 23;
            const int gi = gdelta[b] + j;
            const int lo = gi - (r * NBK + b) * CAP;
            if (lo < CAP) pairs_d[gi] = (int)(v & 0x7FFFFF);
        }
    } else {
        for (int b = tid; b < NBK; b += 256) {
            lcur[b] = lbase[b];
            const int h = hist[b];
            if (h > 0) {
                const int gstart = (r * NBK + b) * CAPB + atomicAdd(&bcnt_s[r * NBK + b], h);
                gdelta[b] = gstart - lbase[b];
            }
        }
        __syncthreads();
        for (int i = tid; i < n; i += 256) {
            const int s = sp[i];
            const int b = s >> 7;
            const int pos = atomicAdd(&lcur[b], 1);
            staging16[pos] = (unsigned short)((b << 7) | (s & 127));
        }
        __syncthreads();
        for (int j = tid; j < n; j += 256) {
            const unsigned short v = staging16[j];
            const int b = v >> 7;
            const int gi = gdelta[b] + j;
            const int lo = gi - (r * NBK + b) * CAPB;
            if (lo < CAPB) pairs_s[gi] = v;
        }
    }
}

// ---------------- merged: dego count (low blocks) + x cast / W' prep (high blocks) ----------------
__global__ __launch_bounds__(256) void dego_setup_kernel(
    const unsigned short* __restrict__ pairs_s, const int* __restrict__ bcnt_s,
    float* __restrict__ dego_r,
    const float* __restrict__ x, unsigned short* __restrict__ xb,
    const float* __restrict__ W1, const float* __restrict__ W2,
    const float* __restrict__ Wlin, unsigned short* __restrict__ Wt1,
    unsigned short* __restrict__ Wt2, unsigned short* __restrict__ WlT)
{
    __shared__ int scnt[BKT];
    const int tid = threadIdx.x;
    const int blk = blockIdx.x;
    if (blk < RR * NBK) {
        const int n2 = min(bcnt_s[blk], CAPB);
        const unsigned short* ps = pairs_s + (size_t)blk * CAPB;
        if (tid < BKT) scnt[tid] = 0;
        __syncthreads();
        for (int i = tid; i < n2; i += 256)
            atomicAdd(&scnt[ps[i] & 127], 1);
        __syncthreads();
        if (tid < BKT) {
            const int r = blk / NBK;
            const int g = (blk % NBK) * BKT + tid;
            if (g < NN)
                dego_r[r * NN + g] = rsqrtf((float)max(scnt[tid], 1));
        }
    } else {
        const int i = (blk - RR * NBK) * 256 + tid;   // 0 .. NN*DD/4-1
        {
            const float4 v = ((const float4*)x)[i];
            ushort4 o;
            o.x = f2b(v.x); o.y = f2b(v.y); o.z = f2b(v.z); o.w = f2b(v.w);
            ((ushort4*)xb)[i] = o;
        }
        if (i < RR * DD * DD) {
            const int r = i >> 14, rem = i & 16383, nn = rem >> 7, k = rem & 127;
            const float diag = (k == nn) ? 1.0f : 0.0f;
            const float w1 = W1[r * DD * DD + k * DD + nn];
            Wt1[i] = f2b(BETA1_ * w1 + diag * (1.0f - BETA1_));
            const float w2 = W2[r * DD * DD + k * DD + nn];
            Wt2[i] = f2b((BETA2_ * w2 + diag * (1.0f - BETA2_)) * (1.0f / 3.0f));
        } else if (i < RR * DD * DD + OUTD * DD) {
            const int j = i - RR * DD * DD;
            const int nn = j >> 7, k = j & 127;
            WlT[j] = f2b(Wlin[k * OUTD + nn]);
        }
    }
}

// ---------------- per-bucket counting sort (in place) -> weighted CSR + degi ----------------
__global__ __launch_bounds__(256) void sort_kernel(
    int* __restrict__ pairs_d, const int* __restrict__ bcnt_d,
    const float* __restrict__ dego_r,
    int* __restrict__ off_g, int* __restrict__ cnt_g, float* __restrict__ degi_r)
{
    __shared__ int stage[CAP];
    __shared__ int cnt[BKT];
    __shared__ int base[BKT];
    __shared__ int pos[BKT];
    const int tid = threadIdx.x;
    const int bid = blockIdx.x;              // r*NBK + b
    const int rr = bid / NBK;
    const int n = min(bcnt_d[bid], CAP);
    int* pp = pairs_d + (size_t)bid * CAP;
    const float* dego = dego_r + (size_t)rr * NN;
    if (tid < BKT) cnt[tid] = 0;
    __syncthreads();
    for (int i = tid; i < n; i += 256) {
        const int p = pp[i];
        stage[i] = p;
        atomicAdd(&cnt[p >> 16], 1);
    }
    __syncthreads();
    if (tid < 64) {
        int carry = 0;
        for (int c0 = 0; c0 < BKT; c0 += 64) {
            const int v = cnt[c0 + tid];
            int incl = v;
            #pragma unroll
            for (int d = 1; d < 64; d <<= 1) {
                const int t = __shfl_up(incl, d, 64);
                if (tid >= d) incl += t;
            }
            base[c0 + tid] = carry + incl - v;
            carry += __shfl(incl, 63, 64);
        }
    }
    __syncthreads();
    if (tid < BKT) {
        pos[tid] = base[tid];
        const int g = (bid % NBK) * BKT + tid;
        if (g < NN) {
            off_g[rr * NN + g] = bid * CAP + base[tid];
            cnt_g[rr * NN + g] = cnt[tid];
            degi_r[rr * NN + g] = rsqrtf((float)max(cnt[tid], 1));
        }
    }
    __syncthreads();
    for (int i = tid; i < n; i += 256) {
        const int p = stage[i];
        const int q = atomicAdd(&pos[p >> 16], 1);
        const int s = p & 0xFFFF;
        pp[q] = s | ((int)f2b(dego[s]) << 16);   // src + folded bf16 weight
    }
}

// ---------------- merged pull (all 3 relations): weighted-CSR bf16 gather + residual ----------------
// 16 lanes per dst node. Software-pipelined: next group's 4 csrw index loads issue in the
// shadow of the current group's 4 row-gathers. Streaming traffic (csrw in, aggb out) is
// non-temporal so L2 capacity is reserved for the 12.8MB gather table (round-6: 44% hit,
// polluted by 38.6MB of write-allocating aggb stores).
__global__ __launch_bounds__(256) void pull_all_kernel(
    const unsigned short* __restrict__ hb,   // gather table [N,128] bf16 (keep cached)
    const unsigned short* __restrict__ xb,   // residual [N,128] bf16
    const int* __restrict__ csrw, const int* __restrict__ off_g,
    const int* __restrict__ cnt_g, const float* __restrict__ degi_r,
    unsigned short* __restrict__ aggb)
{
    const int blk = blockIdx.x;              // r*NPB + nb
    const int r = blk / NPB;
    const int node = (blk % NPB) * 16 + (threadIdx.x >> 4);
    const int lane = threadIdx.x & 15;
    const int gi = r * NN + node;
    const int j0 = off_g[gi];
    const int j1 = j0 + cnt_g[gi];
    const u32x4* hb4 = (const u32x4*)hb;
    float a0 = 0.f, a1 = 0.f, a2 = 0.f, a3 = 0.f, a4 = 0.f, a5 = 0.f, a6 = 0.f, a7 = 0.f;
    int j = j0;
    const int nfull = (j1 - j0) >> 2;
    unsigned int pc0 = 0, pc1 = 0, pc2 = 0, pc3 = 0;
    if (nfull > 0) {
        pc0 = (unsigned int)__builtin_nontemporal_load(csrw + j);
        pc1 = (unsigned int)__builtin_nontemporal_load(csrw + j + 1);
        pc2 = (unsigned int)__builtin_nontemporal_load(csrw + j + 2);
        pc3 = (unsigned int)__builtin_nontemporal_load(csrw + j + 3);
    }
    for (int g = 0; g < nfull; ++g) {
        const u32x4 q0 = hb4[(size_t)(pc0 & 0xFFFF) * 16 + lane];
        const u32x4 q1 = hb4[(size_t)(pc1 & 0xFFFF) * 16 + lane];
        const u32x4 q2 = hb4[(size_t)(pc2 & 0xFFFF) * 16 + lane];
        const u32x4 q3 = hb4[(size_t)(pc3 & 0xFFFF) * 16 + lane];
        const float n0 = bhi(pc0), n1 = bhi(pc1), n2 = bhi(pc2), n3 = bhi(pc3);
        j += 4;
        unsigned int nc0 = 0, nc1 = 0, nc2 = 0, nc3 = 0;
        if (g + 1 < nfull) {                 // prefetch next group's indices (issues under gather latency)
            nc0 = (unsigned int)__builtin_nontemporal_load(csrw + j);
            nc1 = (unsigned int)__builtin_nontemporal_load(csrw + j + 1);
            nc2 = (unsigned int)__builtin_nontemporal_load(csrw + j + 2);
            nc3 = (unsigned int)__builtin_nontemporal_load(csrw + j + 3);
        }
        a0 += blo(q0.x) * n0 + blo(q1.x) * n1 + blo(q2.x) * n2 + blo(q3.x) * n3;
        a1 += bhi(q0.x) * n0 + bhi(q1.x) * n1 + bhi(q2.x) * n2 + bhi(q3.x) * n3;
        a2 += blo(q0.y) * n0 + blo(q1.y) * n1 + blo(q2.y) * n2 + blo(q3.y) * n3;
        a3 += bhi(q0.y) * n0 + bhi(q1.y) * n1 + bhi(q2.y) * n2 + bhi(q3.y) * n3;
        a4 += blo(q0.z) * n0 + blo(q1.z) * n1 + blo(q2.z) * n2 + blo(q3.z) * n3;
        a5 += bhi(q0.z) * n0 + bhi(q1.z) * n1 + bhi(q2.z) * n2 + bhi(q3.z) * n3;
        a6 += blo(q0.w) * n0 + blo(q1.w) * n1 + blo(q2.w) * n2 + blo(q3.w) * n3;
        a7 += bhi(q0.w) * n0 + bhi(q1.w) * n1 + bhi(q2.w) * n2 + bhi(q3.w) * n3;
        pc0 = nc0; pc1 = nc1; pc2 = nc2; pc3 = nc3;
    }
    for (; j < j1; ++j) {
        const unsigned int p0 = (unsigned int)__builtin_nontemporal_load(csrw + j);
        const float n0 = bhi(p0);
        const u32x4 q0 = hb4[(size_t)(p0 & 0xFFFF) * 16 + lane];
        a0 += blo(q0.x) * n0; a1 += bhi(q0.x) * n0;
        a2 += blo(q0.y) * n0; a3 += bhi(q0.y) * n0;
        a4 += blo(q0.z) * n0; a5 += bhi(q0.z) * n0;
        a6 += blo(q0.w) * n0; a7 += bhi(q0.w) * n0;
    }
    const float nd = degi_r[gi] * (1.0f - ALPHA_);
    const u32x4 xq = ((const u32x4*)xb)[(size_t)node * 16 + lane];
    u32x4 o;
    o.x = pack2(a0 * nd + ALPHA_ * blo(xq.x), a1 * nd + ALPHA_ * bhi(xq.x));
    o.y = pack2(a2 * nd + ALPHA_ * blo(xq.y), a3 * nd + ALPHA_ * bhi(xq.y));
    o.z = pack2(a4 * nd + ALPHA_ * blo(xq.z), a5 * nd + ALPHA_ * bhi(xq.z));
    o.w = pack2(a6 * nd + ALPHA_ * blo(xq.w), a7 * nd + ALPHA_ * bhi(xq.w));
    __builtin_nontemporal_store(o, (u32x4*)aggb + (size_t)gi * 16 + lane);
}

// ---------------- MFMA conv: rst_r @ W'_r (+bias-init) [+leaky] summed over r ----------------
// aggb reads are non-temporal (38.6MB read-once) so conv1 doesn't evict h1b from L2 —
// pull2's gather table starts L2-warm.
template<int LIN>
__global__ __launch_bounds__(256) void conv_mfma_kernel(
    const unsigned short* __restrict__ aggb,   // [R][N][128] bf16
    const unsigned short* __restrict__ WtG,    // [R][128][128] bf16, [n][k]
    const float* __restrict__ bias,            // [R,128]
    const unsigned short* __restrict__ WlT,    // [64][128] bf16 (LIN)
    const float* __restrict__ blin,            // [64] (LIN)
    unsigned short* __restrict__ houtb,        // h1b (LIN=0)
    float* __restrict__ outf)                  // out [N,64] (LIN=1)
{
    __shared__ unsigned short WtL[DD * 136];   // 34816 B, stride 136 bf16 (17 uint4)
    uint4* WtL4 = (uint4*)WtL;
    const int tid  = threadIdx.x;
    const int wave = tid >> 6;
    const int lane = tid & 63;
    const int l15  = lane & 15;
    const int q    = lane >> 4;                // 0..3
    const int blockRow = blockIdx.x * 64;
    const int row0 = blockRow + wave * 16;
    const int arow = min(row0 + l15, NN - 1);  // A-frag row (clamped)

    f32x4 o[8];
    if (LIN) {
        #pragma unroll
        for (int ct = 0; ct < 8; ++ct) {
            const int col = ct * 16 + l15;
            const float bv = (bias[col] + bias[DD + col] + bias[2 * DD + col]) * (1.0f / 3.0f);
            o[ct] = (f32x4){bv, bv, bv, bv};
        }
    } else {
        #pragma unroll
        for (int ct = 0; ct < 8; ++ct) o[ct] = (f32x4){0.f, 0.f, 0.f, 0.f};
    }

    short8 a_cur[4], a_nxt[4];
    {
        const u32x4* ap = (const u32x4*)aggb + (size_t)arow * 16 + q;
        #pragma unroll
        for (int ks = 0; ks < 4; ++ks)
            a_cur[ks] = __builtin_bit_cast(short8, __builtin_nontemporal_load(ap + ks * 4));
    }

    for (int r = 0; r < RR; ++r) {
        __syncthreads();                       // prior relation done reading WtL
        const uint4* wg = (const uint4*)(WtG + (size_t)r * DD * DD);
        for (int i = tid; i < DD * 16; i += 256)
            WtL4[(i >> 4) * 17 + (i & 15)] = wg[i];
        if (r + 1 < RR) {                      // prefetch next A-frags (global, independent of WtL)
            const u32x4* ap = (const u32x4*)aggb + ((size_t)(r + 1) * NN + arow) * 16 + q;
            #pragma unroll
            for (int ks = 0; ks < 4; ++ks)
                a_nxt[ks] = __builtin_bit_cast(short8, __builtin_nontemporal_load(ap + ks * 4));
        }
        __syncthreads();                       // WtL staged & visible

        #pragma unroll
        for (int ct = 0; ct < 8; ++ct) {
            f32x4 acc;
            if (LIN) {
                acc = o[ct];
            } else {
                const float bv = bias[r * DD + ct * 16 + l15];
                acc = (f32x4){bv, bv, bv, bv};
            }
            const int nrow = ct * 16 + l15;
            #pragma unroll
            for (int ks = 0; ks < 4; ++ks) {
                const short8 b = __builtin_bit_cast(short8, WtL4[nrow * 17 + ks * 4 + q]);
                acc = __builtin_amdgcn_mfma_f32_16x16x32_bf16(a_cur[ks], b, acc, 0, 0, 0);
            }
            if (LIN) {
                o[ct] = acc;
            } else {
                #pragma unroll
                for (int e = 0; e < 4; ++e) {
                    float v = acc[e];
                    v = v >= 0.f ? v : SLOPE_ * v;
                    o[ct][e] += v * (1.0f / 3.0f);
                }
            }
        }
        #pragma unroll
        for (int ks = 0; ks < 4; ++ks) a_cur[ks] = a_nxt[ks];
    }

    __syncthreads();
    unsigned short* tile = WtL;                // rows 0..63, stride 136
    #pragma unroll
    for (int ct = 0; ct < 8; ++ct) {
        const int col = ct * 16 + l15;
        #pragma unroll
        for (int e = 0; e < 4; ++e) {
            const int lrow = wave * 16 + q * 4 + e;
            tile[lrow * 136 + col] = f2b(o[ct][e]);
        }
    }
    if (LIN) {
        uint4* wl4 = WtL4 + 64 * 17;
        const uint4* wg = (const uint4*)WlT;
        for (int i = tid; i < OUTD * 16; i += 256)
            wl4[(i >> 4) * 17 + (i & 15)] = wg[i];
    }
    __syncthreads();

    if (!LIN) {
        for (int i = tid; i < 64 * 16; i += 256) {
            const int lrow = i >> 4, c = i & 15;
            const int grow = blockRow + lrow;
            if (grow < NN)
                ((uint4*)houtb)[(size_t)grow * 16 + c] = WtL4[lrow * 17 + c];
        }
    } else {
        short8 a2[4];
        const int lrow = wave * 16 + l15;
        #pragma unroll
        for (int ks = 0; ks < 4; ++ks)
            a2[ks] = __builtin_bit_cast(short8, WtL4[lrow * 17 + ks * 4 + q]);
        #pragma unroll
        for (int ct = 0; ct < 4; ++ct) {
            const int col = ct * 16 + l15;
            const float bv = blin[col];
            f32x4 acc = (f32x4){bv, bv, bv, bv};
            #pragma unroll
            for (int ks = 0; ks < 4; ++ks) {
                const short8 b = __builtin_bit_cast(short8, WtL4[(64 + col) * 17 + ks * 4 + q]);
                acc = __builtin_amdgcn_mfma_f32_16x16x32_bf16(a2[ks], b, acc, 0, 0, 0);
            }
            #pragma unroll
            for (int e = 0; e < 4; ++e) {
                const int grow = row0 + q * 4 + e;
                if (grow < NN) outf[(size_t)grow * OUTD + col] = acc[e];
            }
        }
    }
}

extern "C" void kernel_launch(void* const* d_in, const int* in_sizes, int n_in,
                              void* d_out, int out_size, void* d_ws, size_t ws_size,
                              hipStream_t stream)
{
    const float* x    = (const float*)d_in[0];
    const int*   src  = (const int*)  d_in[1];
    const int*   dst  = (const int*)  d_in[2];
    const float* W1   = (const float*)d_in[3];
    const float* b1   = (const float*)d_in[4];
    const float* W2   = (const float*)d_in[5];
    const float* b2   = (const float*)d_in[6];
    const float* Wlin = (const float*)d_in[7];
    const float* blin = (const float*)d_in[8];
    float* out = (float*)d_out;

    // ws layout (4B units): bcnt_d[3*NBK] | bcnt_s[3*NBK] | dego_r[3N] | degi_r[3N] |
    //   off_g[3N] | cnt_g[3N] | pad[2] | pairs_d[3*NBK*CAP] | pairs_s(u16) |
    //   xb(bf16 N*D) | h1b(bf16 N*D) | aggb(bf16 3*N*D) | Wt1 | Wt2 | WlT
    int*   bcnt_d  = (int*)d_ws;
    int*   bcnt_s  = bcnt_d + RR * NBK;
    float* dego_r  = (float*)(bcnt_s + RR * NBK);
    float* degi_r  = dego_r + RR * NN;
    int*   off_g   = (int*)(degi_r + RR * NN);
    int*   cnt_g   = off_g + RR * NN;
    int*   pairs_d = cnt_g + RR * NN + 2;    // +2 -> 16B alignment downstream
    unsigned short* pairs_s = (unsigned short*)(pairs_d + (size_t)RR * NBK * CAP);
    unsigned short* xb   = pairs_s + (size_t)RR * NBK * CAPB;
    unsigned short* h1b  = xb + (size_t)NN * DD;
    unsigned short* aggb = h1b + (size_t)NN * DD;
    unsigned short* Wt1  = aggb + (size_t)RR * NN * DD;
    unsigned short* Wt2  = Wt1 + RR * DD * DD;
    unsigned short* WlT  = Wt2 + RR * DD * DD;

    hipMemsetAsync(bcnt_d, 0, (size_t)2 * RR * NBK * sizeof(int), stream);

    const int gemm_blocks = (NN + 63) / 64;

    // ---- graph preprocessing (once; same graph both layers) ----
    bin_kernel<<<2 * RR * NCH, 256, 0, stream>>>(src, dst, bcnt_d, bcnt_s, pairs_d, pairs_s);
    dego_setup_kernel<<<RR * NBK + SETUPB, 256, 0, stream>>>(
        pairs_s, bcnt_s, dego_r, x, xb, W1, W2, Wlin, Wt1, Wt2, WlT);
    sort_kernel<<<RR * NBK, 256, 0, stream>>>(
        pairs_d, bcnt_d, dego_r, off_g, cnt_g, degi_r);

    // ---- conv1: h1b = bf16( mean_r leaky( rst_r @ W1'_r + b1_r ) ) ----
    pull_all_kernel<<<RR * NPB, 256, 0, stream>>>(
        xb, xb, pairs_d, off_g, cnt_g, degi_r, aggb);
    conv_mfma_kernel<0><<<gemm_blocks, 256, 0, stream>>>(
        aggb, Wt1, b1, nullptr, nullptr, h1b, nullptr);

    // ---- conv2 (+ fused final linear): out = ( sum_r rst_r @ (W2'_r/3) + mean b2 ) @ Wlin + blin ----
    pull_all_kernel<<<RR * NPB, 256, 0, stream>>>(
        h1b, xb, pairs_d, off_g, cnt_g, degi_r, aggb);
    conv_mfma_kernel<1><<<gemm_blocks, 256, 0, stream>>>(
        aggb, Wt2, b2, WlT, blin, nullptr, out);
}

// Round 8
// 409.777 us; speedup vs baseline: 1.0248x; 1.0248x over previous
//
#include <hip/hip_runtime.h>

#define NN    50000
#define DD    128
#define RR    3
#define EE    800000
#define OUTD  64
#define BKT   128                 // nodes per bucket (dst and src binning)
#define NBK   391                 // ceil(NN/BKT)
#define CAP   2560                // per-bucket edge capacity, 4B dst-entries
#define CAPB  2560                // per-bucket edge capacity, 2B src-entries
#define CHUNK 8192                // edges per bin block (98 same-address reserve atomics/counter)
#define NCH   98                  // ceil(EE/CHUNK)
#define SETUPB 6250               // NN*DD/4/256 setup blocks
#define ALPHA_ 0.5f
#define SLOPE_ 0.01f
#define BETA1_ 0.6931471805599453f   // log(2)
#define BETA2_ 0.4054651081081644f   // log(1.5)

typedef __attribute__((ext_vector_type(8))) short short8;   // 8 bf16 = 4 VGPRs
typedef __attribute__((ext_vector_type(4))) float f32x4;
typedef __attribute__((ext_vector_type(4))) unsigned int u32x4;

__device__ __forceinline__ unsigned short f2b(float f) {   // fp32 -> bf16 RNE
    unsigned int u = __builtin_bit_cast(unsigned int, f);
    u += 0x7FFFu + ((u >> 16) & 1u);
    return (unsigned short)(u >> 16);
}
__device__ __forceinline__ unsigned int pack2(float lo, float hi) {
    return (unsigned int)f2b(lo) | ((unsigned int)f2b(hi) << 16);
}
__device__ __forceinline__ float blo(unsigned int w) { return __builtin_bit_cast(float, w << 16); }
__device__ __forceinline__ float bhi(unsigned int w) { return __builtin_bit_cast(float, w & 0xFFFF0000u); }

// ---------------- binning: phase-split LDS bucket-sort (A: by dst>>7, B: by src>>7) ----------------
__global__ __launch_bounds__(256) void bin_kernel(
    const int* __restrict__ src, const int* __restrict__ dst,
    int* __restrict__ bcnt_d, int* __restrict__ bcnt_s,
    int* __restrict__ pairs_d, unsigned short* __restrict__ pairs_s)
{
    __shared__ int hist[NBK];
    __shared__ int lbase[NBK];
    __shared__ int gdelta[NBK];
    __shared__ int lcur[NBK];
    __shared__ unsigned int staging[CHUNK];
    unsigned short* staging16 = (unsigned short*)staging;
    const int tid = threadIdx.x;
    const int blk = blockIdx.x;
    const int phase = (blk >= RR * NCH);
    const int rb = phase ? blk - RR * NCH : blk;
    const int r = rb / NCH;
    const int chunk = rb % NCH;
    const int e0 = chunk * CHUNK;
    const int n = min(CHUNK, EE - e0);
    const int* sp = src + (size_t)r * EE + e0;
    const int* dp = dst + (size_t)r * EE + e0;
    const int* kp = phase ? sp : dp;         // key stream for this phase

    for (int i = tid; i < NBK; i += 256) hist[i] = 0;
    __syncthreads();
    for (int i = tid; i < n; i += 256)
        atomicAdd(&hist[kp[i] >> 7], 1);
    __syncthreads();
    if (tid < 64) {
        int carry = 0;
        for (int c0 = 0; c0 < NBK; c0 += 64) {
            const int idx = c0 + tid;
            const int v = (idx < NBK) ? hist[idx] : 0;
            int incl = v;
            #pragma unroll
            for (int d = 1; d < 64; d <<= 1) {
                const int t = __shfl_up(incl, d, 64);
                if (tid >= d) incl += t;
            }
            if (idx < NBK) lbase[idx] = carry + incl - v;
            carry += __shfl(incl, 63, 64);
        }
    }
    __syncthreads();
    if (!phase) {
        for (int b = tid; b < NBK; b += 256) {
            lcur[b] = lbase[b];
            const int h = hist[b];
            if (h > 0) {
                const int gstart = (r * NBK + b) * CAP + atomicAdd(&bcnt_d[r * NBK + b], h);
                gdelta[b] = gstart - lbase[b];
            }
        }
        __syncthreads();
        for (int i = tid; i < n; i += 256) {
            const int d = dp[i];
            const int b = d >> 7;
            const int pos = atomicAdd(&lcur[b], 1);
            staging[pos] = (unsigned int)sp[i] | ((unsigned int)(d & 127) << 16)
                         | ((unsigned int)b << 23);
        }
        __syncthreads();
        for (int j = tid; j < n; j += 256) {
            const unsigned int v = staging[j];
            const int b = v >> 23;
            const int gi = gdelta[b] + j;
            const int lo = gi - (r * NBK + b) * CAP;
            if (lo < CAP) pairs_d[gi] = (int)(v & 0x7FFFFF);
        }
    } else {
        for (int b = tid; b < NBK; b += 256) {
            lcur[b] = lbase[b];
            const int h = hist[b];
            if (h > 0) {
                const int gstart = (r * NBK + b) * CAPB + atomicAdd(&bcnt_s[r * NBK + b], h);
                gdelta[b] = gstart - lbase[b];
            }
        }
        __syncthreads();
        for (int i = tid; i < n; i += 256) {
            const int s = sp[i];
            const int b = s >> 7;
            const int pos = atomicAdd(&lcur[b], 1);
            staging16[pos] = (unsigned short)((b << 7) | (s & 127));
        }
        __syncthreads();
        for (int j = tid; j < n; j += 256) {
            const unsigned short v = staging16[j];
            const int b = v >> 7;
            const int gi = gdelta[b] + j;
            const int lo = gi - (r * NBK + b) * CAPB;
            if (lo < CAPB) pairs_s[gi] = v;
        }
    }
}

// ---------------- merged: dego count (low blocks) + x cast / W' prep (high blocks) ----------------
__global__ __launch_bounds__(256) void dego_setup_kernel(
    const unsigned short* __restrict__ pairs_s, const int* __restrict__ bcnt_s,
    float* __restrict__ dego_r,
    const float* __restrict__ x, unsigned short* __restrict__ xb,
    const float* __restrict__ W1, const float* __restrict__ W2,
    const float* __restrict__ Wlin, unsigned short* __restrict__ Wt1,
    unsigned short* __restrict__ Wt2, unsigned short* __restrict__ WlT)
{
    __shared__ int scnt[BKT];
    const int tid = threadIdx.x;
    const int blk = blockIdx.x;
    if (blk < RR * NBK) {
        const int n2 = min(bcnt_s[blk], CAPB);
        const unsigned short* ps = pairs_s + (size_t)blk * CAPB;
        if (tid < BKT) scnt[tid] = 0;
        __syncthreads();
        for (int i = tid; i < n2; i += 256)
            atomicAdd(&scnt[ps[i] & 127], 1);
        __syncthreads();
        if (tid < BKT) {
            const int r = blk / NBK;
            const int g = (blk % NBK) * BKT + tid;
            if (g < NN)
                dego_r[r * NN + g] = rsqrtf((float)max(scnt[tid], 1));
        }
    } else {
        const int i = (blk - RR * NBK) * 256 + tid;   // 0 .. NN*DD/4-1
        {
            const float4 v = ((const float4*)x)[i];
            ushort4 o;
            o.x = f2b(v.x); o.y = f2b(v.y); o.z = f2b(v.z); o.w = f2b(v.w);
            ((ushort4*)xb)[i] = o;
        }
        if (i < RR * DD * DD) {
            const int r = i >> 14, rem = i & 16383, nn = rem >> 7, k = rem & 127;
            const float diag = (k == nn) ? 1.0f : 0.0f;
            const float w1 = W1[r * DD * DD + k * DD + nn];
            Wt1[i] = f2b(BETA1_ * w1 + diag * (1.0f - BETA1_));
            const float w2 = W2[r * DD * DD + k * DD + nn];
            Wt2[i] = f2b((BETA2_ * w2 + diag * (1.0f - BETA2_)) * (1.0f / 3.0f));
        } else if (i < RR * DD * DD + OUTD * DD) {
            const int j = i - RR * DD * DD;
            const int nn = j >> 7, k = j & 127;
            WlT[j] = f2b(Wlin[k * OUTD + nn]);
        }
    }
}

// ---------------- per-bucket counting sort (in place) -> weighted CSR + degi ----------------
__global__ __launch_bounds__(256) void sort_kernel(
    int* __restrict__ pairs_d, const int* __restrict__ bcnt_d,
    const float* __restrict__ dego_r,
    int* __restrict__ off_g, int* __restrict__ cnt_g, float* __restrict__ degi_r)
{
    __shared__ int stage[CAP];
    __shared__ int cnt[BKT];
    __shared__ int base[BKT];
    __shared__ int pos[BKT];
    const int tid = threadIdx.x;
    const int bid = blockIdx.x;              // r*NBK + b
    const int rr = bid / NBK;
    const int n = min(bcnt_d[bid], CAP);
    int* pp = pairs_d + (size_t)bid * CAP;
    const float* dego = dego_r + (size_t)rr * NN;
    if (tid < BKT) cnt[tid] = 0;
    __syncthreads();
    for (int i = tid; i < n; i += 256) {
        const int p = pp[i];
        stage[i] = p;
        atomicAdd(&cnt[p >> 16], 1);
    }
    __syncthreads();
    if (tid < 64) {
        int carry = 0;
        for (int c0 = 0; c0 < BKT; c0 += 64) {
            const int v = cnt[c0 + tid];
            int incl = v;
            #pragma unroll
            for (int d = 1; d < 64; d <<= 1) {
                const int t = __shfl_up(incl, d, 64);
                if (tid >= d) incl += t;
            }
            base[c0 + tid] = carry + incl - v;
            carry += __shfl(incl, 63, 64);
        }
    }
    __syncthreads();
    if (tid < BKT) {
        pos[tid] = base[tid];
        const int g = (bid % NBK) * BKT + tid;
        if (g < NN) {
            off_g[rr * NN + g] = bid * CAP + base[tid];
            cnt_g[rr * NN + g] = cnt[tid];
            degi_r[rr * NN + g] = rsqrtf((float)max(cnt[tid], 1));
        }
    }
    __syncthreads();
    for (int i = tid; i < n; i += 256) {
        const int p = stage[i];
        const int q = atomicAdd(&pos[p >> 16], 1);
        const int s = p & 0xFFFF;
        pp[q] = s | ((int)f2b(dego[s]) << 16);   // src + folded bf16 weight
    }
}

// ---------------- FUSED pull+conv: gather (16 lanes/node) -> LDS tile -> MFMA, no aggb ----------------
// 1024 threads/block, 64 nodes/block, 782 blocks = 800K threads (machine-filling; fixes round-1's
// 200K-thread collapse). Per relation: stage W_r || gather || pack tile -> barrier -> 16-wave MFMA
// (wave = rowgrp(4) x colpair(4), o[2]/thread). Removes the 154MB aggb round trip entirely.
template<int LIN>
__global__ __launch_bounds__(1024, 8) void pullconv_kernel(
    const unsigned short* __restrict__ hb,   // gather table [N,128] bf16
    const unsigned short* __restrict__ xb,   // residual [N,128] bf16
    const int* __restrict__ csrw, const int* __restrict__ off_g,
    const int* __restrict__ cnt_g, const float* __restrict__ degi_r,
    const unsigned short* __restrict__ WtG,  // [R][128][128] bf16, [n][k]
    const float* __restrict__ bias,          // [R,128]
    const unsigned short* __restrict__ WlT,  // [64][128] bf16 (LIN)
    const float* __restrict__ blin,          // [64] (LIN)
    unsigned short* __restrict__ houtb,      // h1b (LIN=0)
    float* __restrict__ outf)                // out [N,64] (LIN=1)
{
    __shared__ unsigned short AtL[64 * 136];   // 17408 B agg/h tile, stride 136 bf16 (17 uint4)
    __shared__ unsigned short WtL[DD * 136];   // 34816 B weights
    uint4* AtL4 = (uint4*)AtL;
    uint4* WtL4 = (uint4*)WtL;
    const int tid = threadIdx.x;
    const int blockRow = blockIdx.x * 64;
    // gather role
    const int gnode = tid >> 4;                // 0..63 local node
    const int glane = tid & 15;
    const int gRowC = min(blockRow + gnode, NN - 1);
    // mfma role
    const int wave = tid >> 6;                 // 0..15
    const int lane = tid & 63;
    const int l15  = lane & 15;
    const int q    = lane >> 4;                // 0..3
    const int rg   = wave >> 2;                // row group 0..3 (16 rows each)
    const int cp   = wave & 3;                 // col pair 0..3 (cts cp*2, cp*2+1)
    const int arowL = rg * 16 + l15;           // local A row 0..63

    f32x4 o[2];
    if (LIN) {
        #pragma unroll
        for (int ct2 = 0; ct2 < 2; ++ct2) {
            const int col = (cp * 2 + ct2) * 16 + l15;
            const float bv = (bias[col] + bias[DD + col] + bias[2 * DD + col]) * (1.0f / 3.0f);
            o[ct2] = (f32x4){bv, bv, bv, bv};
        }
    } else {
        o[0] = (f32x4){0.f, 0.f, 0.f, 0.f};
        o[1] = (f32x4){0.f, 0.f, 0.f, 0.f};
    }

    const u32x4* hb4 = (const u32x4*)hb;

    for (int r = 0; r < RR; ++r) {
        __syncthreads();                       // prior relation done reading AtL/WtL
        {   // stage W_r (2 uint4 per thread)
            const uint4* wg = (const uint4*)(WtG + (size_t)r * DD * DD);
            #pragma unroll
            for (int i = tid; i < DD * 16; i += 1024)
                WtL4[(i >> 4) * 17 + (i & 15)] = wg[i];
        }
        // ---- gather (identical math to verified pull_all; 16 lanes/node) ----
        const int gi = r * NN + gRowC;
        const int j0 = off_g[gi];
        const int j1 = j0 + cnt_g[gi];
        float a0 = 0.f, a1 = 0.f, a2 = 0.f, a3 = 0.f, a4 = 0.f, a5 = 0.f, a6 = 0.f, a7 = 0.f;
        int j = j0;
        for (; j + 4 <= j1; j += 4) {
            const unsigned int p0 = csrw[j],     p1 = csrw[j + 1];
            const unsigned int p2 = csrw[j + 2], p3 = csrw[j + 3];
            const float n0 = bhi(p0), n1 = bhi(p1), n2 = bhi(p2), n3 = bhi(p3);
            const u32x4 q0 = hb4[(size_t)(p0 & 0xFFFF) * 16 + glane];
            const u32x4 q1 = hb4[(size_t)(p1 & 0xFFFF) * 16 + glane];
            const u32x4 q2 = hb4[(size_t)(p2 & 0xFFFF) * 16 + glane];
            const u32x4 q3 = hb4[(size_t)(p3 & 0xFFFF) * 16 + glane];
            a0 += blo(q0.x) * n0 + blo(q1.x) * n1 + blo(q2.x) * n2 + blo(q3.x) * n3;
            a1 += bhi(q0.x) * n0 + bhi(q1.x) * n1 + bhi(q2.x) * n2 + bhi(q3.x) * n3;
            a2 += blo(q0.y) * n0 + blo(q1.y) * n1 + blo(q2.y) * n2 + blo(q3.y) * n3;
            a3 += bhi(q0.y) * n0 + bhi(q1.y) * n1 + bhi(q2.y) * n2 + bhi(q3.y) * n3;
            a4 += blo(q0.z) * n0 + blo(q1.z) * n1 + blo(q2.z) * n2 + blo(q3.z) * n3;
            a5 += bhi(q0.z) * n0 + bhi(q1.z) * n1 + bhi(q2.z) * n2 + bhi(q3.z) * n3;
            a6 += blo(q0.w) * n0 + blo(q1.w) * n1 + blo(q2.w) * n2 + blo(q3.w) * n3;
            a7 += bhi(q0.w) * n0 + bhi(q1.w) * n1 + bhi(q2.w) * n2 + bhi(q3.w) * n3;
        }
        for (; j < j1; ++j) {
            const unsigned int p0 = csrw[j];
            const float n0 = bhi(p0);
            const u32x4 q0 = hb4[(size_t)(p0 & 0xFFFF) * 16 + glane];
            a0 += blo(q0.x) * n0; a1 += bhi(q0.x) * n0;
            a2 += blo(q0.y) * n0; a3 += bhi(q0.y) * n0;
            a4 += blo(q0.z) * n0; a5 += bhi(q0.z) * n0;
            a6 += blo(q0.w) * n0; a7 += bhi(q0.w) * n0;
        }
        // ---- residual blend + pack -> LDS tile (rows >= NN hold clamped-dup garbage; never stored) ----
        {
            const float nd = degi_r[gi] * (1.0f - ALPHA_);
            const u32x4 xq = ((const u32x4*)xb)[(size_t)gRowC * 16 + glane];
            uint4 ov;
            ov.x = pack2(a0 * nd + ALPHA_ * blo(xq.x), a1 * nd + ALPHA_ * bhi(xq.x));
            ov.y = pack2(a2 * nd + ALPHA_ * blo(xq.y), a3 * nd + ALPHA_ * bhi(xq.y));
            ov.z = pack2(a4 * nd + ALPHA_ * blo(xq.z), a5 * nd + ALPHA_ * bhi(xq.z));
            ov.w = pack2(a6 * nd + ALPHA_ * blo(xq.w), a7 * nd + ALPHA_ * bhi(xq.w));
            AtL4[gnode * 17 + glane] = ov;
        }
        __syncthreads();                       // tile + W staged

        // ---- MFMA: this wave's 16 rows x 2 col-tiles ----
        short8 a[4];
        #pragma unroll
        for (int ks = 0; ks < 4; ++ks)
            a[ks] = __builtin_bit_cast(short8, AtL4[arowL * 17 + ks * 4 + q]);
        #pragma unroll
        for (int ct2 = 0; ct2 < 2; ++ct2) {
            const int ct = cp * 2 + ct2;
            f32x4 acc;
            if (LIN) {
                acc = o[ct2];
            } else {
                const float bv = bias[r * DD + ct * 16 + l15];
                acc = (f32x4){bv, bv, bv, bv};
            }
            const int nrow = ct * 16 + l15;
            #pragma unroll
            for (int ks = 0; ks < 4; ++ks) {
                const short8 b = __builtin_bit_cast(short8, WtL4[nrow * 17 + ks * 4 + q]);
                acc = __builtin_amdgcn_mfma_f32_16x16x32_bf16(a[ks], b, acc, 0, 0, 0);
            }
            if (LIN) {
                o[ct2] = acc;
            } else {
                #pragma unroll
                for (int e = 0; e < 4; ++e) {
                    float v = acc[e];
                    v = v >= 0.f ? v : SLOPE_ * v;
                    o[ct2][e] += v * (1.0f / 3.0f);
                }
            }
        }
    }

    __syncthreads();                           // done reading AtL/WtL; reuse as output tile
    #pragma unroll
    for (int ct2 = 0; ct2 < 2; ++ct2) {
        const int col = (cp * 2 + ct2) * 16 + l15;
        #pragma unroll
        for (int e = 0; e < 4; ++e) {
            const int lrow = rg * 16 + q * 4 + e;
            AtL[lrow * 136 + col] = f2b(o[ct2][e]);
        }
    }
    if (LIN) {
        uint4* wl4 = WtL4 + 64 * 17;
        const uint4* wg = (const uint4*)WlT;
        #pragma unroll
        for (int i = tid; i < OUTD * 16; i += 1024)
            wl4[(i >> 4) * 17 + (i & 15)] = wg[i];
    }
    __syncthreads();

    if (!LIN) {
        // write h1b: 1024 uint4, 1 per thread
        const int lrow = tid >> 4, c = tid & 15;
        const int grow = blockRow + lrow;
        if (grow < NN)
            ((uint4*)houtb)[(size_t)grow * 16 + c] = AtL4[lrow * 17 + c];
    } else {
        // second GEMM: wave (rg, cp) -> rows rg*16.., out col-tile cp
        short8 a2[4];
        #pragma unroll
        for (int ks = 0; ks < 4; ++ks)
            a2[ks] = __builtin_bit_cast(short8, AtL4[arowL * 17 + ks * 4 + q]);
        const int col = cp * 16 + l15;
        const float bv = blin[col];
        f32x4 acc = (f32x4){bv, bv, bv, bv};
        #pragma unroll
        for (int ks = 0; ks < 4; ++ks) {
            const short8 b = __builtin_bit_cast(short8, WtL4[(64 + col) * 17 + ks * 4 + q]);
            acc = __builtin_amdgcn_mfma_f32_16x16x32_bf16(a2[ks], b, acc, 0, 0, 0);
        }
        #pragma unroll
        for (int e = 0; e < 4; ++e) {
            const int grow = blockRow + rg * 16 + q * 4 + e;
            if (grow < NN) outf[(size_t)grow * OUTD + col] = acc[e];
        }
    }
}

extern "C" void kernel_launch(void* const* d_in, const int* in_sizes, int n_in,
                              void* d_out, int out_size, void* d_ws, size_t ws_size,
                              hipStream_t stream)
{
    const float* x    = (const float*)d_in[0];
    const int*   src  = (const int*)  d_in[1];
    const int*   dst  = (const int*)  d_in[2];
    const float* W1   = (const float*)d_in[3];
    const float* b1   = (const float*)d_in[4];
    const float* W2   = (const float*)d_in[5];
    const float* b2   = (const float*)d_in[6];
    const float* Wlin = (const float*)d_in[7];
    const float* blin = (const float*)d_in[8];
    float* out = (float*)d_out;

    // ws layout (4B units): bcnt_d[3*NBK] | bcnt_s[3*NBK] | dego_r[3N] | degi_r[3N] |
    //   off_g[3N] | cnt_g[3N] | pad[2] | pairs_d[3*NBK*CAP] | pairs_s(u16) |
    //   xb(bf16 N*D) | h1b(bf16 N*D) | aggb(unused, layout kept) | Wt1 | Wt2 | WlT
    int*   bcnt_d  = (int*)d_ws;
    int*   bcnt_s  = bcnt_d + RR * NBK;
    float* dego_r  = (float*)(bcnt_s + RR * NBK);
    float* degi_r  = dego_r + RR * NN;
    int*   off_g   = (int*)(degi_r + RR * NN);
    int*   cnt_g   = off_g + RR * NN;
    int*   pairs_d = cnt_g + RR * NN + 2;    // +2 -> 16B alignment downstream
    unsigned short* pairs_s = (unsigned short*)(pairs_d + (size_t)RR * NBK * CAP);
    unsigned short* xb   = pairs_s + (size_t)RR * NBK * CAPB;
    unsigned short* h1b  = xb + (size_t)NN * DD;
    unsigned short* aggb = h1b + (size_t)NN * DD;   // unused (layout stability)
    unsigned short* Wt1  = aggb + (size_t)RR * NN * DD;
    unsigned short* Wt2  = Wt1 + RR * DD * DD;
    unsigned short* WlT  = Wt2 + RR * DD * DD;

    hipMemsetAsync(bcnt_d, 0, (size_t)2 * RR * NBK * sizeof(int), stream);

    const int gemm_blocks = (NN + 63) / 64;

    // ---- graph preprocessing (once; same graph both layers) ----
    bin_kernel<<<2 * RR * NCH, 256, 0, stream>>>(src, dst, bcnt_d, bcnt_s, pairs_d, pairs_s);
    dego_setup_kernel<<<RR * NBK + SETUPB, 256, 0, stream>>>(
        pairs_s, bcnt_s, dego_r, x, xb, W1, W2, Wlin, Wt1, Wt2, WlT);
    sort_kernel<<<RR * NBK, 256, 0, stream>>>(
        pairs_d, bcnt_d, dego_r, off_g, cnt_g, degi_r);

    // ---- layer 1 fused: h1b = bf16( mean_r leaky( rst_r @ W1'_r + b1_r ) ) ----
    pullconv_kernel<0><<<gemm_blocks, 1024, 0, stream>>>(
        xb, xb, pairs_d, off_g, cnt_g, degi_r, Wt1, b1, nullptr, nullptr, h1b, nullptr);

    // ---- layer 2 fused (+ final linear): out = ( sum_r rst_r @ (W2'_r/3) + mean b2 ) @ Wlin + blin ----
    pullconv_kernel<1><<<gemm_blocks, 1024, 0, stream>>>(
        h1b, xb, pairs_d, off_g, cnt_g, degi_r, Wt2, b2, WlT, blin, nullptr, out);
}

// Round 9
// 376.893 us; speedup vs baseline: 1.1142x; 1.0872x over previous
//
#include <hip/hip_runtime.h>

#define NN    50000
#define DD    128
#define RR    3
#define EE    800000
#define OUTD  64
#define BKT   128                 // nodes per bucket (dst and src binning)
#define NBK   391                 // ceil(NN/BKT)
#define CAP   2560                // per-bucket edge capacity, 4B dst-entries
#define CAPB  2560                // per-bucket edge capacity, 2B src-entries
#define CHUNK 8192                // edges per bin block (98 same-address reserve atomics/counter)
#define NCH   98                  // ceil(EE/CHUNK)
#define NPB   3125                // NN/16 pull blocks per relation
#define SETUPB 6250               // NN*DD/4/256 setup blocks
#define MCB   49                  // M-matrix (48) + C-vector (1) prep blocks
#define PGB   391                 // ceil(NN/128) pgemm blocks
#define P64B  3125                // NN/16 pull64 blocks
#define ALPHA_ 0.5f
#define SLOPE_ 0.01f
#define BETA1_ 0.6931471805599453f   // log(2)
#define BETA2_ 0.4054651081081644f   // log(1.5)

typedef __attribute__((ext_vector_type(8))) short short8;   // 8 bf16 = 4 VGPRs
typedef __attribute__((ext_vector_type(4))) float f32x4;
typedef __attribute__((ext_vector_type(4))) unsigned int u32x4;

__device__ __forceinline__ unsigned short f2b(float f) {   // fp32 -> bf16 RNE
    unsigned int u = __builtin_bit_cast(unsigned int, f);
    u += 0x7FFFu + ((u >> 16) & 1u);
    return (unsigned short)(u >> 16);
}
__device__ __forceinline__ unsigned int pack2(float lo, float hi) {
    return (unsigned int)f2b(lo) | ((unsigned int)f2b(hi) << 16);
}
__device__ __forceinline__ float blo(unsigned int w) { return __builtin_bit_cast(float, w << 16); }
__device__ __forceinline__ float bhi(unsigned int w) { return __builtin_bit_cast(float, w & 0xFFFF0000u); }

// ---------------- binning: phase-split LDS bucket-sort (A: by dst>>7, B: by src>>7) ----------------
__global__ __launch_bounds__(256) void bin_kernel(
    const int* __restrict__ src, const int* __restrict__ dst,
    int* __restrict__ bcnt_d, int* __restrict__ bcnt_s,
    int* __restrict__ pairs_d, unsigned short* __restrict__ pairs_s)
{
    __shared__ int hist[NBK];
    __shared__ int lbase[NBK];
    __shared__ int gdelta[NBK];
    __shared__ int lcur[NBK];
    __shared__ unsigned int staging[CHUNK];
    unsigned short* staging16 = (unsigned short*)staging;
    const int tid = threadIdx.x;
    const int blk = blockIdx.x;
    const int phase = (blk >= RR * NCH);
    const int rb = phase ? blk - RR * NCH : blk;
    const int r = rb / NCH;
    const int chunk = rb % NCH;
    const int e0 = chunk * CHUNK;
    const int n = min(CHUNK, EE - e0);
    const int* sp = src + (size_t)r * EE + e0;
    const int* dp = dst + (size_t)r * EE + e0;
    const int* kp = phase ? sp : dp;         // key stream for this phase

    for (int i = tid; i < NBK; i += 256) hist[i] = 0;
    __syncthreads();
    for (int i = tid; i < n; i += 256)
        atomicAdd(&hist[kp[i] >> 7], 1);
    __syncthreads();
    if (tid < 64) {
        int carry = 0;
        for (int c0 = 0; c0 < NBK; c0 += 64) {
            const int idx = c0 + tid;
            const int v = (idx < NBK) ? hist[idx] : 0;
            int incl = v;
            #pragma unroll
            for (int d = 1; d < 64; d <<= 1) {
                const int t = __shfl_up(incl, d, 64);
                if (tid >= d) incl += t;
            }
            if (idx < NBK) lbase[idx] = carry + incl - v;
            carry += __shfl(incl, 63, 64);
        }
    }
    __syncthreads();
    if (!phase) {
        for (int b = tid; b < NBK; b += 256) {
            lcur[b] = lbase[b];
            const int h = hist[b];
            if (h > 0) {
                const int gstart = (r * NBK + b) * CAP + atomicAdd(&bcnt_d[r * NBK + b], h);
                gdelta[b] = gstart - lbase[b];
            }
        }
        __syncthreads();
        for (int i = tid; i < n; i += 256) {
            const int d = dp[i];
            const int b = d >> 7;
            const int pos = atomicAdd(&lcur[b], 1);
            staging[pos] = (unsigned int)sp[i] | ((unsigned int)(d & 127) << 16)
                         | ((unsigned int)b << 23);
        }
        __syncthreads();
        for (int j = tid; j < n; j += 256) {
            const unsigned int v = staging[j];
            const int b = v >> 23;
            const int gi = gdelta[b] + j;
            const int lo = gi - (r * NBK + b) * CAP;
            if (lo < CAP) pairs_d[gi] = (int)(v & 0x7FFFFF);
        }
    } else {
        for (int b = tid; b < NBK; b += 256) {
            lcur[b] = lbase[b];
            const int h = hist[b];
            if (h > 0) {
                const int gstart = (r * NBK + b) * CAPB + atomicAdd(&bcnt_s[r * NBK + b], h);
                gdelta[b] = gstart - lbase[b];
            }
        }
        __syncthreads();
        for (int i = tid; i < n; i += 256) {
            const int s = sp[i];
            const int b = s >> 7;
            const int pos = atomicAdd(&lcur[b], 1);
            staging16[pos] = (unsigned short)((b << 7) | (s & 127));
        }
        __syncthreads();
        for (int j = tid; j < n; j += 256) {
            const unsigned short v = staging16[j];
            const int b = v >> 7;
            const int gi = gdelta[b] + j;
            const int lo = gi - (r * NBK + b) * CAPB;
            if (lo < CAPB) pairs_s[gi] = v;
        }
    }
}

// ---------------- merged: dego count | x cast / W' prep | M = W2'@Wlin/3 and C prep ----------------
__global__ __launch_bounds__(256) void dego_setup_kernel(
    const unsigned short* __restrict__ pairs_s, const int* __restrict__ bcnt_s,
    float* __restrict__ dego_r,
    const float* __restrict__ x, unsigned short* __restrict__ xb,
    const float* __restrict__ W1, const float* __restrict__ W2,
    const float* __restrict__ Wlin, unsigned short* __restrict__ Wt1,
    unsigned short* __restrict__ Wt2, unsigned short* __restrict__ WlT,
    const float* __restrict__ b2, const float* __restrict__ blin,
    unsigned short* __restrict__ MT, float* __restrict__ Cbuf)
{
    __shared__ int scnt[BKT];
    const int tid = threadIdx.x;
    const int blk = blockIdx.x;
    if (blk < RR * NBK) {
        const int n2 = min(bcnt_s[blk], CAPB);
        const unsigned short* ps = pairs_s + (size_t)blk * CAPB;
        if (tid < BKT) scnt[tid] = 0;
        __syncthreads();
        for (int i = tid; i < n2; i += 256)
            atomicAdd(&scnt[ps[i] & 127], 1);
        __syncthreads();
        if (tid < BKT) {
            const int r = blk / NBK;
            const int g = (blk % NBK) * BKT + tid;
            if (g < NN)
                dego_r[r * NN + g] = rsqrtf((float)max(scnt[tid], 1));
        }
    } else if (blk < RR * NBK + SETUPB) {
        const int i = (blk - RR * NBK) * 256 + tid;   // 0 .. NN*DD/4-1
        {
            const float4 v = ((const float4*)x)[i];
            ushort4 o;
            o.x = f2b(v.x); o.y = f2b(v.y); o.z = f2b(v.z); o.w = f2b(v.w);
            ((ushort4*)xb)[i] = o;
        }
        if (i < RR * DD * DD) {
            const int r = i >> 14, rem = i & 16383, nn = rem >> 7, k = rem & 127;
            const float diag = (k == nn) ? 1.0f : 0.0f;
            const float w1 = W1[r * DD * DD + k * DD + nn];
            Wt1[i] = f2b(BETA1_ * w1 + diag * (1.0f - BETA1_));
            const float w2 = W2[r * DD * DD + k * DD + nn];
            Wt2[i] = f2b((BETA2_ * w2 + diag * (1.0f - BETA2_)) * (1.0f / 3.0f));
        } else if (i < RR * DD * DD + OUTD * DD) {
            const int j = i - RR * DD * DD;
            const int nn = j >> 7, k = j & 127;
            WlT[j] = f2b(Wlin[k * OUTD + nn]);
        }
    } else {
        // ---- M_r^T[o][k] = ((1-b2)/3)*Wlin[k][o] + (b2/3)*sum_n W2[r][k][n]*Wlin[n][o]; C[o] ----
        const int mb = blk - RR * NBK - SETUPB;
        if (mb < MCB - 1) {
            const int base = (mb * 256 + tid) * 2;
            #pragma unroll
            for (int ii = 0; ii < 2; ++ii) {
                const int gidx = base + ii;           // flat = r*8192 + o*128 + k
                const int r = gidx >> 13;
                const int rem = gidx & 8191;
                const int o = rem >> 7, k = rem & 127;
                float s = 0.f;
                for (int nn = 0; nn < DD; ++nn)
                    s += W2[r * DD * DD + k * DD + nn] * Wlin[nn * OUTD + o];
                MT[gidx] = f2b((BETA2_ / 3.0f) * s + ((1.0f - BETA2_) / 3.0f) * Wlin[k * OUTD + o]);
            }
        } else {
            if (tid < OUTD) {
                float s = blin[tid];
                for (int nn = 0; nn < DD; ++nn) {
                    const float mb2 = (b2[nn] + b2[DD + nn] + b2[2 * DD + nn]) * (1.0f / 3.0f);
                    s += mb2 * Wlin[nn * OUTD + tid];
                }
                Cbuf[tid] = s;
            }
        }
    }
}

// ---------------- per-bucket counting sort (in place) -> weighted CSR + degi ----------------
__global__ __launch_bounds__(256) void sort_kernel(
    int* __restrict__ pairs_d, const int* __restrict__ bcnt_d,
    const float* __restrict__ dego_r,
    int* __restrict__ off_g, int* __restrict__ cnt_g, float* __restrict__ degi_r)
{
    __shared__ int stage[CAP];
    __shared__ int cnt[BKT];
    __shared__ int base[BKT];
    __shared__ int pos[BKT];
    const int tid = threadIdx.x;
    const int bid = blockIdx.x;              // r*NBK + b
    const int rr = bid / NBK;
    const int n = min(bcnt_d[bid], CAP);
    int* pp = pairs_d + (size_t)bid * CAP;
    const float* dego = dego_r + (size_t)rr * NN;
    if (tid < BKT) cnt[tid] = 0;
    __syncthreads();
    for (int i = tid; i < n; i += 256) {
        const int p = pp[i];
        stage[i] = p;
        atomicAdd(&cnt[p >> 16], 1);
    }
    __syncthreads();
    if (tid < 64) {
        int carry = 0;
        for (int c0 = 0; c0 < BKT; c0 += 64) {
            const int v = cnt[c0 + tid];
            int incl = v;
            #pragma unroll
            for (int d = 1; d < 64; d <<= 1) {
                const int t = __shfl_up(incl, d, 64);
                if (tid >= d) incl += t;
            }
            base[c0 + tid] = carry + incl - v;
            carry += __shfl(incl, 63, 64);
        }
    }
    __syncthreads();
    if (tid < BKT) {
        pos[tid] = base[tid];
        const int g = (bid % NBK) * BKT + tid;
        if (g < NN) {
            off_g[rr * NN + g] = bid * CAP + base[tid];
            cnt_g[rr * NN + g] = cnt[tid];
            degi_r[rr * NN + g] = rsqrtf((float)max(cnt[tid], 1));
        }
    }
    __syncthreads();
    for (int i = tid; i < n; i += 256) {
        const int p = stage[i];
        const int q = atomicAdd(&pos[p >> 16], 1);
        const int s = p & 0xFFFF;
        pp[q] = s | ((int)f2b(dego[s]) << 16);   // src + folded bf16 weight
    }
}

// ---------------- merged pull (all 3 relations): weighted-CSR bf16 gather + residual ----------------
// (round-6 verified: 16 lanes/node, 16B/lane, unroll-4, register accumulate)
__global__ __launch_bounds__(256) void pull_all_kernel(
    const unsigned short* __restrict__ hb,   // gather table [N,128] bf16
    const unsigned short* __restrict__ xb,   // residual [N,128] bf16
    const int* __restrict__ csrw, const int* __restrict__ off_g,
    const int* __restrict__ cnt_g, const float* __restrict__ degi_r,
    unsigned short* __restrict__ aggb)
{
    const int blk = blockIdx.x;              // r*NPB + nb
    const int r = blk / NPB;
    const int node = (blk % NPB) * 16 + (threadIdx.x >> 4);
    const int lane = threadIdx.x & 15;
    const int gi = r * NN + node;
    const int j0 = off_g[gi];
    const int j1 = j0 + cnt_g[gi];
    const u32x4* hb4 = (const u32x4*)hb;
    float a0 = 0.f, a1 = 0.f, a2 = 0.f, a3 = 0.f, a4 = 0.f, a5 = 0.f, a6 = 0.f, a7 = 0.f;
    int j = j0;
    for (; j + 4 <= j1; j += 4) {
        const unsigned int p0 = csrw[j],     p1 = csrw[j + 1];
        const unsigned int p2 = csrw[j + 2], p3 = csrw[j + 3];
        const float n0 = bhi(p0), n1 = bhi(p1), n2 = bhi(p2), n3 = bhi(p3);
        const u32x4 q0 = hb4[(size_t)(p0 & 0xFFFF) * 16 + lane];
        const u32x4 q1 = hb4[(size_t)(p1 & 0xFFFF) * 16 + lane];
        const u32x4 q2 = hb4[(size_t)(p2 & 0xFFFF) * 16 + lane];
        const u32x4 q3 = hb4[(size_t)(p3 & 0xFFFF) * 16 + lane];
        a0 += blo(q0.x) * n0 + blo(q1.x) * n1 + blo(q2.x) * n2 + blo(q3.x) * n3;
        a1 += bhi(q0.x) * n0 + bhi(q1.x) * n1 + bhi(q2.x) * n2 + bhi(q3.x) * n3;
        a2 += blo(q0.y) * n0 + blo(q1.y) * n1 + blo(q2.y) * n2 + blo(q3.y) * n3;
        a3 += bhi(q0.y) * n0 + bhi(q1.y) * n1 + bhi(q2.y) * n2 + bhi(q3.y) * n3;
        a4 += blo(q0.z) * n0 + blo(q1.z) * n1 + blo(q2.z) * n2 + blo(q3.z) * n3;
        a5 += bhi(q0.z) * n0 + bhi(q1.z) * n1 + bhi(q2.z) * n2 + bhi(q3.z) * n3;
        a6 += blo(q0.w) * n0 + blo(q1.w) * n1 + blo(q2.w) * n2 + blo(q3.w) * n3;
        a7 += bhi(q0.w) * n0 + bhi(q1.w) * n1 + bhi(q2.w) * n2 + bhi(q3.w) * n3;
    }
    for (; j < j1; ++j) {
        const unsigned int p0 = csrw[j];
        const float n0 = bhi(p0);
        const u32x4 q0 = hb4[(size_t)(p0 & 0xFFFF) * 16 + lane];
        a0 += blo(q0.x) * n0; a1 += bhi(q0.x) * n0;
        a2 += blo(q0.y) * n0; a3 += bhi(q0.y) * n0;
        a4 += blo(q0.z) * n0; a5 += bhi(q0.z) * n0;
        a6 += blo(q0.w) * n0; a7 += bhi(q0.w) * n0;
    }
    const float nd = degi_r[gi] * (1.0f - ALPHA_);
    const u32x4 xq = ((const u32x4*)xb)[(size_t)node * 16 + lane];
    u32x4 o;
    o.x = pack2(a0 * nd + ALPHA_ * blo(xq.x), a1 * nd + ALPHA_ * bhi(xq.x));
    o.y = pack2(a2 * nd + ALPHA_ * blo(xq.y), a3 * nd + ALPHA_ * bhi(xq.y));
    o.z = pack2(a4 * nd + ALPHA_ * blo(xq.z), a5 * nd + ALPHA_ * bhi(xq.z));
    o.w = pack2(a6 * nd + ALPHA_ * blo(xq.w), a7 * nd + ALPHA_ * bhi(xq.w));
    ((u32x4*)aggb)[(size_t)gi * 16 + lane] = o;
}

// ---------------- MFMA conv1: rst_r @ W1'_r + b1 -> leaky -> mean over r -> h1b ----------------
template<int LIN>
__global__ __launch_bounds__(256) void conv_mfma_kernel(
    const unsigned short* __restrict__ aggb,   // [R][N][128] bf16
    const unsigned short* __restrict__ WtG,    // [R][128][128] bf16, [n][k]
    const float* __restrict__ bias,            // [R,128]
    const unsigned short* __restrict__ WlT,    // unused (LIN=0)
    const float* __restrict__ blin,            // unused (LIN=0)
    unsigned short* __restrict__ houtb,        // h1b
    float* __restrict__ outf)                  // unused (LIN=0)
{
    __shared__ unsigned short WtL[DD * 136];   // 34816 B, stride 136 bf16 (17 uint4)
    uint4* WtL4 = (uint4*)WtL;
    const int tid  = threadIdx.x;
    const int wave = tid >> 6;
    const int lane = tid & 63;
    const int l15  = lane & 15;
    const int q    = lane >> 4;                // 0..3
    const int blockRow = blockIdx.x * 64;
    const int row0 = blockRow + wave * 16;
    const int arow = min(row0 + l15, NN - 1);  // A-frag row (clamped)

    f32x4 o[8];
    if (LIN) {
        #pragma unroll
        for (int ct = 0; ct < 8; ++ct) {
            const int col = ct * 16 + l15;
            const float bv = (bias[col] + bias[DD + col] + bias[2 * DD + col]) * (1.0f / 3.0f);
            o[ct] = (f32x4){bv, bv, bv, bv};
        }
    } else {
        #pragma unroll
        for (int ct = 0; ct < 8; ++ct) o[ct] = (f32x4){0.f, 0.f, 0.f, 0.f};
    }

    short8 a_cur[4], a_nxt[4];
    {
        const uint4* ap = (const uint4*)aggb + (size_t)arow * 16 + q;
        #pragma unroll
        for (int ks = 0; ks < 4; ++ks)
            a_cur[ks] = __builtin_bit_cast(short8, ap[ks * 4]);
    }

    for (int r = 0; r < RR; ++r) {
        __syncthreads();
        const uint4* wg = (const uint4*)(WtG + (size_t)r * DD * DD);
        for (int i = tid; i < DD * 16; i += 256)
            WtL4[(i >> 4) * 17 + (i & 15)] = wg[i];
        if (r + 1 < RR) {
            const uint4* ap = (const uint4*)aggb + ((size_t)(r + 1) * NN + arow) * 16 + q;
            #pragma unroll
            for (int ks = 0; ks < 4; ++ks)
                a_nxt[ks] = __builtin_bit_cast(short8, ap[ks * 4]);
        }
        __syncthreads();

        #pragma unroll
        for (int ct = 0; ct < 8; ++ct) {
            f32x4 acc;
            if (LIN) {
                acc = o[ct];
            } else {
                const float bv = bias[r * DD + ct * 16 + l15];
                acc = (f32x4){bv, bv, bv, bv};
            }
            const int nrow = ct * 16 + l15;
            #pragma unroll
            for (int ks = 0; ks < 4; ++ks) {
                const short8 b = __builtin_bit_cast(short8, WtL4[nrow * 17 + ks * 4 + q]);
                acc = __builtin_amdgcn_mfma_f32_16x16x32_bf16(a_cur[ks], b, acc, 0, 0, 0);
            }
            if (LIN) {
                o[ct] = acc;
            } else {
                #pragma unroll
                for (int e = 0; e < 4; ++e) {
                    float v = acc[e];
                    v = v >= 0.f ? v : SLOPE_ * v;
                    o[ct][e] += v * (1.0f / 3.0f);
                }
            }
        }
        #pragma unroll
        for (int ks = 0; ks < 4; ++ks) a_cur[ks] = a_nxt[ks];
    }

    __syncthreads();
    unsigned short* tile = WtL;                // rows 0..63, stride 136
    #pragma unroll
    for (int ct = 0; ct < 8; ++ct) {
        const int col = ct * 16 + l15;
        #pragma unroll
        for (int e = 0; e < 4; ++e) {
            const int lrow = wave * 16 + q * 4 + e;
            tile[lrow * 136 + col] = f2b(o[ct][e]);
        }
    }
    __syncthreads();
    for (int i = tid; i < 64 * 16; i += 256) {
        const int lrow = i >> 4, c = i & 15;
        const int grow = blockRow + lrow;
        if (grow < NN)
            ((uint4*)houtb)[(size_t)grow * 16 + c] = WtL4[lrow * 17 + c];
    }
}

// ---------------- pgemm: P_r = h1b @ M_r (r=0..2), Q = ALPHA * x @ sum_r M_r  (all N x 64 bf16) ----
__global__ __launch_bounds__(512) void pgemm_kernel(
    const unsigned short* __restrict__ h1b,  // [N][128] bf16
    const unsigned short* __restrict__ xb,   // [N][128] bf16
    const unsigned short* __restrict__ MT,   // [R][64][128] bf16 (o-major, k inner)
    unsigned short* __restrict__ Pb,         // [R][N][64] bf16
    unsigned short* __restrict__ Qb)         // [N][64] bf16
{
    __shared__ unsigned short MTL[RR * 64 * 136];   // 52224 B, stride 136 (17 uint4)
    uint4* MTL4 = (uint4*)MTL;
    const int tid  = threadIdx.x;
    const int wave = tid >> 6;                 // 0..7
    const int lane = tid & 63;
    const int l15  = lane & 15;
    const int q    = lane >> 4;
    const int blockRow = blockIdx.x * 128;
    const int row0 = blockRow + wave * 16;
    const int arow = min(row0 + l15, NN - 1);

    {   // stage all three M^T matrices (3*64*16 = 3072 uint4)
        const uint4* mg = (const uint4*)MT;
        for (int i = tid; i < RR * 64 * 16; i += 512)
            MTL4[(i >> 4) * 17 + (i & 15)] = mg[i];
    }
    short8 ah[4], ax[4];
    {
        const uint4* hp = (const uint4*)h1b + (size_t)arow * 16 + q;
        const uint4* xp = (const uint4*)xb + (size_t)arow * 16 + q;
        #pragma unroll
        for (int ks = 0; ks < 4; ++ks) {
            ah[ks] = __builtin_bit_cast(short8, hp[ks * 4]);
            ax[ks] = __builtin_bit_cast(short8, xp[ks * 4]);
        }
    }
    __syncthreads();

    // P_r = h1 @ M_r
    for (int r = 0; r < RR; ++r) {
        #pragma unroll
        for (int ct = 0; ct < 4; ++ct) {
            f32x4 acc = (f32x4){0.f, 0.f, 0.f, 0.f};
            const int orow = r * 64 + ct * 16 + l15;
            #pragma unroll
            for (int ks = 0; ks < 4; ++ks) {
                const short8 b = __builtin_bit_cast(short8, MTL4[orow * 17 + ks * 4 + q]);
                acc = __builtin_amdgcn_mfma_f32_16x16x32_bf16(ah[ks], b, acc, 0, 0, 0);
            }
            #pragma unroll
            for (int e = 0; e < 4; ++e) {
                const int grow = row0 + q * 4 + e;
                if (grow < NN)
                    Pb[((size_t)r * NN + grow) * OUTD + ct * 16 + l15] = f2b(acc[e]);
            }
        }
    }
    // Q = ALPHA * x @ (M0+M1+M2)
    #pragma unroll
    for (int ct = 0; ct < 4; ++ct) {
        f32x4 acc = (f32x4){0.f, 0.f, 0.f, 0.f};
        for (int r = 0; r < RR; ++r) {
            const int orow = r * 64 + ct * 16 + l15;
            #pragma unroll
            for (int ks = 0; ks < 4; ++ks) {
                const short8 b = __builtin_bit_cast(short8, MTL4[orow * 17 + ks * 4 + q]);
                acc = __builtin_amdgcn_mfma_f32_16x16x32_bf16(ax[ks], b, acc, 0, 0, 0);
            }
        }
        #pragma unroll
        for (int e = 0; e < 4; ++e) {
            const int grow = row0 + q * 4 + e;
            if (grow < NN)
                Qb[(size_t)grow * OUTD + ct * 16 + l15] = f2b(acc[e] * ALPHA_);
        }
    }
}

// ---------------- pull64: out[v] = sum_r (1-a)*degi_r[v] * gather(P_r) + Q[v] + C ----------------
// 16 lanes/node, 8B/lane (row = 128B = one L2 line), r-loop accumulated in registers (no atomics).
__global__ __launch_bounds__(256) void pull64_kernel(
    const unsigned short* __restrict__ Pb,   // [R][N][64] bf16
    const unsigned short* __restrict__ Qb,   // [N][64] bf16
    const float* __restrict__ Cbuf,          // [64] f32
    const int* __restrict__ csrw, const int* __restrict__ off_g,
    const int* __restrict__ cnt_g, const float* __restrict__ degi_r,
    float* __restrict__ outf)                // [N][64] f32
{
    const int node = blockIdx.x * 16 + (threadIdx.x >> 4);
    const int lane = threadIdx.x & 15;
    const uint2* P2 = (const uint2*)Pb;
    float t0, t1, t2, t3;
    {
        const uint2 qq = ((const uint2*)Qb)[(size_t)node * 16 + lane];
        const float4 cv = ((const float4*)Cbuf)[lane];
        t0 = blo(qq.x) + cv.x; t1 = bhi(qq.x) + cv.y;
        t2 = blo(qq.y) + cv.z; t3 = bhi(qq.y) + cv.w;
    }
    for (int r = 0; r < RR; ++r) {
        const int gi = r * NN + node;
        const int j0 = off_g[gi];
        const int j1 = j0 + cnt_g[gi];
        const uint2* Pr = P2 + (size_t)r * NN * 16;
        float a0 = 0.f, a1 = 0.f, a2 = 0.f, a3 = 0.f;
        int j = j0;
        for (; j + 4 <= j1; j += 4) {
            const unsigned int p0 = csrw[j],     p1 = csrw[j + 1];
            const unsigned int p2 = csrw[j + 2], p3 = csrw[j + 3];
            const float n0 = bhi(p0), n1 = bhi(p1), n2 = bhi(p2), n3 = bhi(p3);
            const uint2 q0 = Pr[(size_t)(p0 & 0xFFFF) * 16 + lane];
            const uint2 q1 = Pr[(size_t)(p1 & 0xFFFF) * 16 + lane];
            const uint2 q2 = Pr[(size_t)(p2 & 0xFFFF) * 16 + lane];
            const uint2 q3 = Pr[(size_t)(p3 & 0xFFFF) * 16 + lane];
            a0 += blo(q0.x) * n0 + blo(q1.x) * n1 + blo(q2.x) * n2 + blo(q3.x) * n3;
            a1 += bhi(q0.x) * n0 + bhi(q1.x) * n1 + bhi(q2.x) * n2 + bhi(q3.x) * n3;
            a2 += blo(q0.y) * n0 + blo(q1.y) * n1 + blo(q2.y) * n2 + blo(q3.y) * n3;
            a3 += bhi(q0.y) * n0 + bhi(q1.y) * n1 + bhi(q2.y) * n2 + bhi(q3.y) * n3;
        }
        for (; j < j1; ++j) {
            const unsigned int p0 = csrw[j];
            const float n0 = bhi(p0);
            const uint2 q0 = Pr[(size_t)(p0 & 0xFFFF) * 16 + lane];
            a0 += blo(q0.x) * n0; a1 += bhi(q0.x) * n0;
            a2 += blo(q0.y) * n0; a3 += bhi(q0.y) * n0;
        }
        const float nd = degi_r[gi] * (1.0f - ALPHA_);
        t0 += a0 * nd; t1 += a1 * nd; t2 += a2 * nd; t3 += a3 * nd;
    }
    float4 ov; ov.x = t0; ov.y = t1; ov.z = t2; ov.w = t3;
    ((float4*)outf)[(size_t)node * 16 + lane] = ov;
}

extern "C" void kernel_launch(void* const* d_in, const int* in_sizes, int n_in,
                              void* d_out, int out_size, void* d_ws, size_t ws_size,
                              hipStream_t stream)
{
    const float* x    = (const float*)d_in[0];
    const int*   src  = (const int*)  d_in[1];
    const int*   dst  = (const int*)  d_in[2];
    const float* W1   = (const float*)d_in[3];
    const float* b1   = (const float*)d_in[4];
    const float* W2   = (const float*)d_in[5];
    const float* b2   = (const float*)d_in[6];
    const float* Wlin = (const float*)d_in[7];
    const float* blin = (const float*)d_in[8];
    float* out = (float*)d_out;

    // ws layout (4B units): bcnt_d[3*NBK] | bcnt_s[3*NBK] | dego_r[3N] | degi_r[3N] |
    //   off_g[3N] | cnt_g[3N] | pad[2] | pairs_d[3*NBK*CAP] | pairs_s(u16) |
    //   xb | h1b | aggb (later aliased by Pb+Qb) | Wt1 | Wt2 | WlT | MT | Cbuf
    int*   bcnt_d  = (int*)d_ws;
    int*   bcnt_s  = bcnt_d + RR * NBK;
    float* dego_r  = (float*)(bcnt_s + RR * NBK);
    float* degi_r  = dego_r + RR * NN;
    int*   off_g   = (int*)(degi_r + RR * NN);
    int*   cnt_g   = off_g + RR * NN;
    int*   pairs_d = cnt_g + RR * NN + 2;    // +2 -> 16B alignment downstream
    unsigned short* pairs_s = (unsigned short*)(pairs_d + (size_t)RR * NBK * CAP);
    unsigned short* xb   = pairs_s + (size_t)RR * NBK * CAPB;
    unsigned short* h1b  = xb + (size_t)NN * DD;
    unsigned short* aggb = h1b + (size_t)NN * DD;
    unsigned short* Wt1  = aggb + (size_t)RR * NN * DD;
    unsigned short* Wt2  = Wt1 + RR * DD * DD;
    unsigned short* WlT  = Wt2 + RR * DD * DD;
    unsigned short* MT   = WlT + OUTD * DD;            // [R][64][128] bf16
    float*          Cbuf = (float*)(MT + RR * DD * OUTD);
    // Pb/Qb alias aggb region (aggb dead after conv1; stream-ordered safe):
    unsigned short* Pb = aggb;                          // RR*NN*64 u16 (9.6M of 19.2M)
    unsigned short* Qb = aggb + (size_t)RR * NN * OUTD; // NN*64 u16

    hipMemsetAsync(bcnt_d, 0, (size_t)2 * RR * NBK * sizeof(int), stream);

    const int gemm_blocks = (NN + 63) / 64;

    // ---- graph preprocessing (once; same graph both layers) ----
    bin_kernel<<<2 * RR * NCH, 256, 0, stream>>>(src, dst, bcnt_d, bcnt_s, pairs_d, pairs_s);
    dego_setup_kernel<<<RR * NBK + SETUPB + MCB, 256, 0, stream>>>(
        pairs_s, bcnt_s, dego_r, x, xb, W1, W2, Wlin, Wt1, Wt2, WlT, b2, blin, MT, Cbuf);
    sort_kernel<<<RR * NBK, 256, 0, stream>>>(
        pairs_d, bcnt_d, dego_r, off_g, cnt_g, degi_r);

    // ---- conv1: h1b = bf16( mean_r leaky( rst_r @ W1'_r + b1_r ) ) ----
    pull_all_kernel<<<RR * NPB, 256, 0, stream>>>(
        xb, xb, pairs_d, off_g, cnt_g, degi_r, aggb);
    conv_mfma_kernel<0><<<gemm_blocks, 256, 0, stream>>>(
        aggb, Wt1, b1, nullptr, nullptr, h1b, nullptr);

    // ---- layer 2 via associativity: project h1 into 64-dim per relation, THEN gather ----
    pgemm_kernel<<<PGB, 512, 0, stream>>>(h1b, xb, MT, Pb, Qb);
    pull64_kernel<<<P64B, 256, 0, stream>>>(
        Pb, Qb, Cbuf, pairs_d, off_g, cnt_g, degi_r, out);
}